// Round 3
// baseline (516.770 us; speedup 1.0000x reference)
//
#include <hip/hip_runtime.h>
#include <hip/hip_bf16.h>
#include <math.h>

#define D 192
#define RPB 16                       // rows per block -> M = 32 tokens
typedef unsigned short u16;
typedef __attribute__((ext_vector_type(8))) short short8;   // 8 bf16 (4 VGPRs)
typedef __attribute__((ext_vector_type(4))) float float4v;  // MFMA C/D

__device__ __forceinline__ float b2f(u16 u){ union{unsigned i; float f;}c; c.i=(unsigned)u<<16; return c.f; }
__device__ __forceinline__ u16  f2b(float f){
    union{float f; unsigned i;}c; c.f=f;
    unsigned r = c.i + 0x7FFFu + ((c.i>>16)&1u);   // RTNE
    return (u16)(r>>16);
}
__device__ __forceinline__ float sel4(float a0,float a1,float a2,float a3,int s){
    return s==0?a0:(s==1?a1:(s==2?a2:a3));
}

// ---- bf16 weight arena in d_ws: 16x32 wave-tiles, element offsets ----
// swz(n,k) = ((n>>4)*(K>>5) + (k>>5))*512 + (n&15)*32 + (k&31)
#define WP_OFF   0
#define WT_OFF   36864
#define INW_OFF  73728
#define OUTW_OFF 184320
#define FW1_OFF  221184
#define FW2_OFF  294912
#define CW1_OFF  368640
#define FPW_OFF  405504
#define W_TOTAL  430080            // elements; 860160 bytes

__global__ __launch_bounds__(256)
void cvt_weights(const float* __restrict__ Wp, const float* __restrict__ Wt,
                 const float* __restrict__ in_w, const float* __restrict__ out_w,
                 const float* __restrict__ fw1, const float* __restrict__ fw2,
                 const float* __restrict__ cw1, const float* __restrict__ fpw,
                 u16* __restrict__ ws)
{
    int idx = blockIdx.x * 256 + threadIdx.x;
    if (idx >= W_TOTAL) return;
    const float* src; int off; int K = 192;
    if      (idx < WT_OFF)   { src = Wp;   off = WP_OFF; }
    else if (idx < INW_OFF)  { src = Wt;   off = WT_OFF; }
    else if (idx < OUTW_OFF) { src = in_w; off = INW_OFF; }
    else if (idx < FW1_OFF)  { src = out_w;off = OUTW_OFF; }
    else if (idx < FW2_OFF)  { src = fw1;  off = FW1_OFF; }
    else if (idx < CW1_OFF)  { src = fw2;  off = FW2_OFF; K = 384; }
    else if (idx < FPW_OFF)  { src = cw1;  off = CW1_OFF; }
    else                     { src = fpw;  off = FPW_OFF; }
    int lin = idx - off;
    int n = lin / K, k = lin - n*K;
    int swz = ((n>>4)*(K>>5) + (k>>5))*512 + ((n&15)<<5) + (k&31);
    ws[off + swz] = f2b(src[lin]);
}

// A-frag: lane holds A[m = mt*16 + lane16][k = quad*8 + j] for k-step ks (k += 32*ks)
template<int KT, int MT>
__device__ __forceinline__ void load_afrags(short8 (&A)[MT][KT], const u16* base,
                                            int stride, int lane16, int quad)
{
    #pragma unroll
    for (int mt = 0; mt < MT; ++mt)
        #pragma unroll
        for (int ks = 0; ks < KT; ++ks)
            A[mt][ks] = *(const short8*)(base + (mt*16 + lane16)*stride + ks*32 + quad*8);
}

// C tile (M=MT*16, N=NTW*4 waves*16): B streamed from swizzled global bf16 tiles.
// C/D layout: row = quad*4 + reg, col = lane16 (m89-verified).
template<int KT, int MT, int NTW>
__device__ __forceinline__ void run_gemm(const short8 (&A)[MT][KT],
    const u16* __restrict__ wsb, const float* __restrict__ bias,
    u16* dst, float* dstf, int dstride,
    const u16* resid, int rstride, bool relu, int rmul, int roff,
    int wave, int lane16, int quad)
{
    #pragma unroll
    for (int i = 0; i < NTW; ++i) {
        int nt = wave + 4*i, n0 = nt*16;
        float4v c[MT];
        #pragma unroll
        for (int mt = 0; mt < MT; ++mt) c[mt] = (float4v){0.f,0.f,0.f,0.f};
        #pragma unroll
        for (int ks = 0; ks < KT; ++ks) {
            short8 b = *(const short8*)(wsb + (size_t)((nt*KT + ks)<<9) + (lane16<<5) + (quad<<3));
            #pragma unroll
            for (int mt = 0; mt < MT; ++mt)
                c[mt] = __builtin_amdgcn_mfma_f32_16x16x32_bf16(A[mt][ks], b, c[mt], 0,0,0);
        }
        float bv = bias[n0 + lane16];
        #pragma unroll
        for (int mt = 0; mt < MT; ++mt)
            #pragma unroll
            for (int ii = 0; ii < 4; ++ii) {
                int dr = (mt*16 + quad*4 + ii)*rmul + roff;
                float v = c[mt][ii] + bv;
                if (resid) v += b2f(resid[dr*rstride + n0 + lane16]);
                if (relu)  v = fmaxf(v, 0.f);
                if (dst) dst [dr*dstride + n0 + lane16] = f2b(v);
                else     dstf[dr*dstride + n0 + lane16] = v;
            }
    }
}

// ---- LDS arena (u16 elements), peak live = 12800 u16 = 25 KB ----
#define S1 200
#define SH 392
#define A_INP 0          // 16x200 inputs P   (dead after proj)
#define A_INT 3200       // 16x200 inputs T   (dead after proj)
#define A_SEQ 6400       // 32x200 seq        (x1 written in-place over it)
// satt_w: float[4][16][12] = 1536 u16 at arena[0] (over dead inputs, qkv phase)
#define A_CTX 0          // 32x200 ctx (over inputs/satt_w; dead after out-proj frags)
#define A_X1  6400       // 32x200 post-LN1 x1 (in-place over seq; dead after FFN1 frags)
#define A_H   0          // 32x392 = 12544 h (over ctx+x1, barrier-protected)
#define A_Z   0          // 16x200 z  (over dead h)
#define A_CH  3200       // 16x200 cls hidden
#define A_FPF 6400       // 16x128 f32 = 4096 u16
#define ARENA_U16 12800

__global__ __launch_bounds__(256, 5)
void fusion_mfma_kernel(
    const float* __restrict__ perc, const float* __restrict__ tech,
    const float* __restrict__ bp,   const float* __restrict__ bt,
    const float* __restrict__ in_b, const float* __restrict__ out_b,
    const float* __restrict__ fb1,  const float* __restrict__ fb2,
    const float* __restrict__ ln1g, const float* __restrict__ ln1b,
    const float* __restrict__ ln2g, const float* __restrict__ ln2b,
    const float* __restrict__ cb1,  const float* __restrict__ cw2,
    const float* __restrict__ cb2,  const float* __restrict__ fpb,
    const u16*   __restrict__ ws,
    float* __restrict__ out, int B)
{
    __shared__ __align__(16) u16 arena[ARENA_U16];
    __shared__ __align__(16) float satt[16][3][4];   // softmax probs [r][h][qt*2+kt]
    __shared__ float wavered[4][32][2];              // per-wave LN partials
    __shared__ float smu[32], srs[32], srn[16];

    const int tid = threadIdx.x;
    const int wave = tid >> 6, lane = tid & 63;
    const int lane16 = lane & 15, quad = lane >> 4;
    const int row0 = blockIdx.x * RPB;
    float* fpf = (float*)(arena + A_FPF);

    // ---- stage inputs -> bf16 LDS ----
    #pragma unroll
    for (int it = 0; it < 3; ++it) {
        int idx = it*256 + tid;           // 768 = 2 arrays * 16 rows * 24 groups-of-8
        int arr = idx >= 384 ? 1 : 0;
        int rem = arr ? idx - 384 : idx;
        int r = rem / 24, g = rem - r*24;
        const float* src = arr ? tech : perc;
        const float4* s4 = (const float4*)(src + (size_t)(row0 + r)*D + g*8);
        float4 lo = s4[0], hi = s4[1];
        short8 o;
        o[0]=(short)f2b(lo.x); o[1]=(short)f2b(lo.y); o[2]=(short)f2b(lo.z); o[3]=(short)f2b(lo.w);
        o[4]=(short)f2b(hi.x); o[5]=(short)f2b(hi.y); o[6]=(short)f2b(hi.z); o[7]=(short)f2b(hi.w);
        *(short8*)(arena + (arr ? A_INT : A_INP) + r*S1 + g*8) = o;
    }
    __syncthreads();

    // ---- proj_p / proj_t -> seq (tokens interleaved 2r / 2r+1) ----
    {
        short8 A1[1][6];
        load_afrags<6,1>(A1, arena + A_INP, S1, lane16, quad);
        run_gemm<6,1,3>(A1, ws + WP_OFF, bp, arena + A_SEQ, nullptr, S1,
                        nullptr, 0, false, 2, 0, wave, lane16, quad);
        load_afrags<6,1>(A1, arena + A_INT, S1, lane16, quad);
        run_gemm<6,1,3>(A1, ws + WT_OFF, bt, arena + A_SEQ, nullptr, S1,
                        nullptr, 0, false, 2, 1, wave, lane16, quad);
    }
    __syncthreads();

    // ---- qkv: K -> regs, Q fused into score partials; nothing to LDS but satt_w ----
    short8 A2[2][6];
    load_afrags<6,2>(A2, arena + A_SEQ, S1, lane16, quad);
    {
        float4v kreg[3][2];
        #pragma unroll
        for (int i = 0; i < 3; ++i) {
            int nt = wave + 4*i;
            kreg[i][0] = (float4v){0,0,0,0}; kreg[i][1] = (float4v){0,0,0,0};
            #pragma unroll
            for (int ks = 0; ks < 6; ++ks) {
                short8 b = *(const short8*)(ws + INW_OFF + 192*192 + ((nt*6+ks)<<9) + (lane16<<5) + (quad<<3));
                kreg[i][0] = __builtin_amdgcn_mfma_f32_16x16x32_bf16(A2[0][ks], b, kreg[i][0], 0,0,0);
                kreg[i][1] = __builtin_amdgcn_mfma_f32_16x16x32_bf16(A2[1][ks], b, kreg[i][1], 0,0,0);
            }
            float bv = in_b[192 + nt*16 + lane16];
            #pragma unroll
            for (int mt = 0; mt < 2; ++mt)
                #pragma unroll
                for (int ii = 0; ii < 4; ++ii) kreg[i][mt][ii] += bv;
        }
        float* satt_w = (float*)arena;   // [4][16][12] over dead inputs
        #pragma unroll
        for (int i = 0; i < 3; ++i) {    // head i
            int nt = wave + 4*i;
            float4v cq[2] = {(float4v){0,0,0,0},(float4v){0,0,0,0}};
            #pragma unroll
            for (int ks = 0; ks < 6; ++ks) {
                short8 b = *(const short8*)(ws + INW_OFF + ((nt*6+ks)<<9) + (lane16<<5) + (quad<<3));
                cq[0] = __builtin_amdgcn_mfma_f32_16x16x32_bf16(A2[0][ks], b, cq[0], 0,0,0);
                cq[1] = __builtin_amdgcn_mfma_f32_16x16x32_bf16(A2[1][ks], b, cq[1], 0,0,0);
            }
            float bv = in_b[nt*16 + lane16];
            float sc[2][2][4];           // [mt][p][qt*2+kt], compile-time indexed
            #pragma unroll
            for (int mt = 0; mt < 2; ++mt)
                #pragma unroll
                for (int p = 0; p < 2; ++p) {
                    float q0 = cq[mt][2*p] + bv, q1 = cq[mt][2*p+1] + bv;
                    float k0 = kreg[i][mt][2*p], k1 = kreg[i][mt][2*p+1];
                    sc[mt][p][0] = q0*k0; sc[mt][p][1] = q0*k1;
                    sc[mt][p][2] = q1*k0; sc[mt][p][3] = q1*k1;
                }
            #pragma unroll
            for (int mt = 0; mt < 2; ++mt)
                #pragma unroll
                for (int p = 0; p < 2; ++p)
                    #pragma unroll
                    for (int c = 0; c < 4; ++c) {
                        float v = sc[mt][p][c];
                        v += __shfl_xor(v, 1); v += __shfl_xor(v, 2);
                        v += __shfl_xor(v, 4); v += __shfl_xor(v, 8);
                        sc[mt][p][c] = v;
                    }
            if ((lane16 >> 2) == i) {
                int c = lane16 & 3;
                #pragma unroll
                for (int mt = 0; mt < 2; ++mt)
                    #pragma unroll
                    for (int p = 0; p < 2; ++p) {
                        float vv = sel4(sc[mt][p][0], sc[mt][p][1], sc[mt][p][2], sc[mt][p][3], c);
                        satt_w[(wave*16 + (2*quad + p + 8*mt))*12 + i*4 + c] = vv;
                    }
            }
        }
    }
    __syncthreads();

    // ---- softmax finalize (96 threads) ----
    if (tid < 96) {
        const float* satt_w = (const float*)arena;
        int r = tid / 6, rem = tid - r*6;
        int h = rem >> 1, qt = rem & 1;
        float s0 = 0.f, s1 = 0.f;
        #pragma unroll
        for (int w = 0; w < 4; ++w) {
            s0 += satt_w[(w*16 + r)*12 + h*4 + qt*2 + 0];
            s1 += satt_w[(w*16 + r)*12 + h*4 + qt*2 + 1];
        }
        s0 *= 0.125f; s1 *= 0.125f;
        float m = fmaxf(s0, s1);
        float e0 = expf(s0 - m), e1 = expf(s1 - m);
        float inv = 1.f / (e0 + e1);
        satt[r][h][qt*2 + 0] = e0 * inv;
        satt[r][h][qt*2 + 1] = e1 * inv;
    }
    __syncthreads();

    // ---- V-GEMM fused with ctx (writes ctx over dead inputs/satt_w) ----
    #pragma unroll
    for (int i = 0; i < 3; ++i) {
        int nt = wave + 4*i, col = nt*16 + lane16;
        float4v cv[2] = {(float4v){0,0,0,0},(float4v){0,0,0,0}};
        #pragma unroll
        for (int ks = 0; ks < 6; ++ks) {
            short8 b = *(const short8*)(ws + INW_OFF + 384*192 + ((nt*6+ks)<<9) + (lane16<<5) + (quad<<3));
            cv[0] = __builtin_amdgcn_mfma_f32_16x16x32_bf16(A2[0][ks], b, cv[0], 0,0,0);
            cv[1] = __builtin_amdgcn_mfma_f32_16x16x32_bf16(A2[1][ks], b, cv[1], 0,0,0);
        }
        float bv = in_b[384 + col];
        #pragma unroll
        for (int mt = 0; mt < 2; ++mt)
            #pragma unroll
            for (int p = 0; p < 2; ++p) {
                float v0 = cv[mt][2*p] + bv, v1 = cv[mt][2*p+1] + bv;
                int r = 2*quad + p + 8*mt;
                float4 pa = *(const float4*)&satt[r][i][0];
                arena[A_CTX + (2*r    )*S1 + col] = f2b(pa.x*v0 + pa.y*v1);
                arena[A_CTX + (2*r + 1)*S1 + col] = f2b(pa.z*v0 + pa.w*v1);
            }
    }
    __syncthreads();

    // ---- out-proj + residual(seq) -> x1 kept in REGS; LN1 partials fused ----
    float4v x1r[3][2];
    {
        short8 Ac[2][6];
        load_afrags<6,2>(Ac, arena + A_CTX, S1, lane16, quad);
        #pragma unroll
        for (int i = 0; i < 3; ++i) {
            int nt = wave + 4*i, col = nt*16 + lane16;
            x1r[i][0] = (float4v){0,0,0,0}; x1r[i][1] = (float4v){0,0,0,0};
            #pragma unroll
            for (int ks = 0; ks < 6; ++ks) {
                short8 b = *(const short8*)(ws + OUTW_OFF + ((nt*6+ks)<<9) + (lane16<<5) + (quad<<3));
                x1r[i][0] = __builtin_amdgcn_mfma_f32_16x16x32_bf16(Ac[0][ks], b, x1r[i][0], 0,0,0);
                x1r[i][1] = __builtin_amdgcn_mfma_f32_16x16x32_bf16(Ac[1][ks], b, x1r[i][1], 0,0,0);
            }
            float bv = out_b[col];
            #pragma unroll
            for (int mt = 0; mt < 2; ++mt)
                #pragma unroll
                for (int ii = 0; ii < 4; ++ii) {
                    int row = quad*4 + ii + 16*mt;
                    x1r[i][mt][ii] += bv + b2f(arena[A_SEQ + row*S1 + col]);
                }
        }
        // LN1 row partials (8 rows/thread over its 3 cols) -> butterfly -> wavered
        float sr[2][4], s2r[2][4];
        #pragma unroll
        for (int mt = 0; mt < 2; ++mt)
            #pragma unroll
            for (int ii = 0; ii < 4; ++ii) {
                float a0 = x1r[0][mt][ii], a1 = x1r[1][mt][ii], a2 = x1r[2][mt][ii];
                float s = a0 + a1 + a2;
                float s2 = a0*a0 + a1*a1 + a2*a2;
                s  += __shfl_xor(s, 1);  s  += __shfl_xor(s, 2);
                s  += __shfl_xor(s, 4);  s  += __shfl_xor(s, 8);
                s2 += __shfl_xor(s2, 1); s2 += __shfl_xor(s2, 2);
                s2 += __shfl_xor(s2, 4); s2 += __shfl_xor(s2, 8);
                sr[mt][ii] = s; s2r[mt][ii] = s2;
            }
        int l = lane16;
        float rowlo = sel4(sr[0][0], sr[0][1], sr[0][2], sr[0][3], l & 3);
        float rowhi = sel4(sr[1][0], sr[1][1], sr[1][2], sr[1][3], l & 3);
        float row2lo = sel4(s2r[0][0], s2r[0][1], s2r[0][2], s2r[0][3], l & 3);
        float row2hi = sel4(s2r[1][0], s2r[1][1], s2r[1][2], s2r[1][3], l & 3);
        float sv = (l & 4) ? rowhi : rowlo;
        float s2v = (l & 4) ? row2hi : row2lo;
        float val = (l & 8) ? s2v : sv;
        wavered[wave][quad*4 + (l & 3) + 16*((l >> 2) & 1)][l >> 3] = val;
    }
    __syncthreads();
    if (tid < 32) {
        float s = 0.f, s2 = 0.f;
        #pragma unroll
        for (int w = 0; w < 4; ++w) { s += wavered[w][tid][0]; s2 += wavered[w][tid][1]; }
        float mu = s * (1.f/192.f);
        float var = s2 * (1.f/192.f) - mu*mu;
        smu[tid] = mu; srs[tid] = rsqrtf(var + 1e-5f);
    }
    __syncthreads();

    // ---- LN1 apply to regs + write post-LN x1 to LDS (for FFN1 frags) ----
    #pragma unroll
    for (int i = 0; i < 3; ++i) {
        int col = (wave + 4*i)*16 + lane16;
        float g = ln1g[col], bb = ln1b[col];
        #pragma unroll
        for (int mt = 0; mt < 2; ++mt)
            #pragma unroll
            for (int ii = 0; ii < 4; ++ii) {
                int row = quad*4 + ii + 16*mt;
                float x = (x1r[i][mt][ii] - smu[row]) * srs[row] * g + bb;
                x1r[i][mt][ii] = x;
                arena[A_X1 + row*S1 + col] = f2b(x);
            }
    }
    __syncthreads();

    // ---- FFN1 (relu) -> h; h overwrites ctx+x1 (frags loaded, then barrier) ----
    {
        short8 Ax[2][6];
        load_afrags<6,2>(Ax, arena + A_X1, S1, lane16, quad);
        __syncthreads();            // all frag loads done before h overwrites x1
        run_gemm<6,2,6>(Ax, ws + FW1_OFF, fb1, arena + A_H, nullptr, SH,
                        nullptr, 0, true, 1, 0, wave, lane16, quad);
    }
    __syncthreads();

    // ---- FFN2 (K=384) + reg-resid -> x2 in REGS; LN2 partials fused ----
    {
        float4v c2[3][2];
        #pragma unroll
        for (int i = 0; i < 3; ++i) { c2[i][0] = (float4v){0,0,0,0}; c2[i][1] = (float4v){0,0,0,0}; }
        #pragma unroll
        for (int kc = 0; kc < 2; ++kc) {
            short8 Af[2][6];
            load_afrags<6,2>(Af, arena + A_H + kc*192, SH, lane16, quad);
            #pragma unroll
            for (int i = 0; i < 3; ++i) {
                int nt = wave + 4*i;
                #pragma unroll
                for (int ks = 0; ks < 6; ++ks) {
                    short8 b = *(const short8*)(ws + FW2_OFF + ((nt*12 + kc*6 + ks)<<9) + (lane16<<5) + (quad<<3));
                    c2[i][0] = __builtin_amdgcn_mfma_f32_16x16x32_bf16(Af[0][ks], b, c2[i][0], 0,0,0);
                    c2[i][1] = __builtin_amdgcn_mfma_f32_16x16x32_bf16(Af[1][ks], b, c2[i][1], 0,0,0);
                }
            }
        }
        #pragma unroll
        for (int i = 0; i < 3; ++i) {
            float bv = fb2[(wave + 4*i)*16 + lane16];
            #pragma unroll
            for (int mt = 0; mt < 2; ++mt)
                #pragma unroll
                for (int ii = 0; ii < 4; ++ii)
                    c2[i][mt][ii] += bv + x1r[i][mt][ii];
        }
        // LN2 partials
        float sr[2][4], s2r[2][4];
        #pragma unroll
        for (int mt = 0; mt < 2; ++mt)
            #pragma unroll
            for (int ii = 0; ii < 4; ++ii) {
                float a0 = c2[0][mt][ii], a1 = c2[1][mt][ii], a2 = c2[2][mt][ii];
                float s = a0 + a1 + a2;
                float s2 = a0*a0 + a1*a1 + a2*a2;
                s  += __shfl_xor(s, 1);  s  += __shfl_xor(s, 2);
                s  += __shfl_xor(s, 4);  s  += __shfl_xor(s, 8);
                s2 += __shfl_xor(s2, 1); s2 += __shfl_xor(s2, 2);
                s2 += __shfl_xor(s2, 4); s2 += __shfl_xor(s2, 8);
                sr[mt][ii] = s; s2r[mt][ii] = s2;
            }
        int l = lane16;
        float rowlo = sel4(sr[0][0], sr[0][1], sr[0][2], sr[0][3], l & 3);
        float rowhi = sel4(sr[1][0], sr[1][1], sr[1][2], sr[1][3], l & 3);
        float row2lo = sel4(s2r[0][0], s2r[0][1], s2r[0][2], s2r[0][3], l & 3);
        float row2hi = sel4(s2r[1][0], s2r[1][1], s2r[1][2], s2r[1][3], l & 3);
        float sv = (l & 4) ? rowhi : rowlo;
        float s2v = (l & 4) ? row2hi : row2lo;
        float val = (l & 8) ? s2v : sv;
        wavered[wave][quad*4 + (l & 3) + 16*((l >> 2) & 1)][l >> 3] = val;
        __syncthreads();
        if (tid < 32) {
            float s = 0.f, s2 = 0.f;
            #pragma unroll
            for (int w = 0; w < 4; ++w) { s += wavered[w][tid][0]; s2 += wavered[w][tid][1]; }
            float mu = s * (1.f/192.f);
            float var = s2 * (1.f/192.f) - mu*mu;
            smu[tid] = mu; srs[tid] = rsqrtf(var + 1e-5f);
        }
        __syncthreads();
        // ---- LN2 apply + token-mean in-thread -> z (over dead h) ----
        #pragma unroll
        for (int i = 0; i < 3; ++i) {
            int col = (wave + 4*i)*16 + lane16;
            float g = ln2g[col], bb = ln2b[col];
            #pragma unroll
            for (int mt = 0; mt < 2; ++mt)
                #pragma unroll
                for (int p = 0; p < 2; ++p) {
                    int r = 2*quad + p + 8*mt;
                    float n0v = (c2[i][mt][2*p]   - smu[2*r  ]) * srs[2*r  ] * g + bb;
                    float n1v = (c2[i][mt][2*p+1] - smu[2*r+1]) * srs[2*r+1] * g + bb;
                    arena[A_Z + r*S1 + col] = f2b(0.5f*(n0v + n1v));
                }
        }
    }
    __syncthreads();

    // ---- heads: cls1 (relu -> ch), fingerprint (f32 -> fpf) ----
    {
        short8 A1[1][6];
        load_afrags<6,1>(A1, arena + A_Z, S1, lane16, quad);
        run_gemm<6,1,3>(A1, ws + CW1_OFF, cb1, arena + A_CH, nullptr, S1,
                        nullptr, 0, true, 1, 0, wave, lane16, quad);
        run_gemm<6,1,2>(A1, ws + FPW_OFF, fpb, nullptr, fpf, 128,
                        nullptr, 0, false, 1, 0, wave, lane16, quad);
    }
    __syncthreads();

    // ---- cls2+sigmoid (waves 0-2) || fp-norm partials (wave 3) ----
    if (tid < 192) {
        int g4 = tid >> 2, sub = tid & 3;
        int r = g4 / 3, cc = g4 - r*3;
        const float* w = cw2 + (size_t)cc * D + sub*48;
        const u16* hr = arena + A_CH + r*S1 + sub*48;
        float a = 0.f;
        #pragma unroll
        for (int i = 0; i < 6; ++i) {
            short8 hv = *(const short8*)(hr + i*8);
            float4 w0 = ((const float4*)w)[2*i], w1 = ((const float4*)w)[2*i+1];
            float wv[8] = {w0.x,w0.y,w0.z,w0.w,w1.x,w1.y,w1.z,w1.w};
            #pragma unroll
            for (int j = 0; j < 8; ++j) a += wv[j] * b2f((u16)hv[j]);
        }
        a += __shfl_xor(a, 1); a += __shfl_xor(a, 2);
        if (sub == 0) {
            a += cb2[cc];
            out[(size_t)cc * B + (size_t)(row0 + r)] = 1.f / (1.f + expf(-a));
        }
    } else {
        int t = tid - 192;               // 64 threads: 16 rows x 4-lane split
        int r = t >> 2, sub = t & 3;
        const float4* fp4 = (const float4*)(fpf + r*128 + sub*32);
        float s2 = 0.f;
        #pragma unroll
        for (int i = 0; i < 8; ++i) {
            float4 v = fp4[i];
            s2 += v.x*v.x + v.y*v.y + v.z*v.z + v.w*v.w;
        }
        s2 += __shfl_xor(s2, 1); s2 += __shfl_xor(s2, 2);
        if (sub == 0) srn[r] = 1.f / fmaxf(sqrtf(s2), 1e-12f);
    }
    __syncthreads();

    // ---- fingerprint writeout (float4) ----
    #pragma unroll
    for (int it = 0; it < 2; ++it) {
        int idx = it*256 + tid;          // 512 = 16 r * 32 float4
        int r = idx >> 5, c = idx & 31;
        float4 v = ((const float4*)(fpf + r*128))[c];
        float sc = srn[r];
        float4 o; o.x = v.x*sc; o.y = v.y*sc; o.z = v.z*sc; o.w = v.w*sc;
        ((float4*)(out + (size_t)3*B + (size_t)(row0 + r)*128))[c] = o;
    }
}

extern "C" void kernel_launch(void* const* d_in, const int* in_sizes, int n_in,
                              void* d_out, int out_size, void* d_ws, size_t ws_size,
                              hipStream_t stream) {
    if (ws_size < (size_t)W_TOTAL * 2) return;   // visible failure -> ws too small

    const float* perc = (const float*)d_in[0];
    const float* tech = (const float*)d_in[1];
    const float* Wp   = (const float*)d_in[2];
    const float* bp   = (const float*)d_in[3];
    const float* Wt   = (const float*)d_in[4];
    const float* bt   = (const float*)d_in[5];
    const float* in_w = (const float*)d_in[6];
    const float* in_b = (const float*)d_in[7];
    const float* ow   = (const float*)d_in[8];
    const float* ob   = (const float*)d_in[9];
    const float* fw1  = (const float*)d_in[10];
    const float* fb1  = (const float*)d_in[11];
    const float* fw2  = (const float*)d_in[12];
    const float* fb2  = (const float*)d_in[13];
    const float* ln1g = (const float*)d_in[14];
    const float* ln1b = (const float*)d_in[15];
    const float* ln2g = (const float*)d_in[16];
    const float* ln2b = (const float*)d_in[17];
    const float* cw1  = (const float*)d_in[18];
    const float* cb1  = (const float*)d_in[19];
    const float* cw2  = (const float*)d_in[20];
    const float* cb2  = (const float*)d_in[21];
    const float* fpw  = (const float*)d_in[22];
    const float* fpb  = (const float*)d_in[23];

    u16* ws = (u16*)d_ws;
    int B = in_sizes[0] / D;

    hipLaunchKernelGGL(cvt_weights, dim3((W_TOTAL + 255)/256), dim3(256), 0, stream,
                       Wp, Wt, in_w, ow, fw1, fw2, cw1, fpw, ws);

    hipLaunchKernelGGL(fusion_mfma_kernel, dim3(B / RPB), dim3(256), 0, stream,
                       perc, tech, bp, bt, in_b, ob, fb1, fb2,
                       ln1g, ln1b, ln2g, ln2b, cb1, cw2, cb2, fpb,
                       ws, (float*)d_out, B);
}

// Round 4
// 421.740 us; speedup vs baseline: 1.2253x; 1.2253x over previous
//
#include <hip/hip_runtime.h>
#include <hip/hip_bf16.h>
#include <math.h>

#define D 192
#define RPB 16                       // rows per block -> M = 32 tokens
typedef unsigned short u16;
typedef __attribute__((ext_vector_type(8))) short short8;   // 8 bf16 (4 VGPRs)
typedef __attribute__((ext_vector_type(4))) float float4v;  // MFMA C/D

__device__ __forceinline__ float b2f(u16 u){ union{unsigned i; float f;}c; c.i=(unsigned)u<<16; return c.f; }
__device__ __forceinline__ u16  f2b(float f){
    union{float f; unsigned i;}c; c.f=f;
    unsigned r = c.i + 0x7FFFu + ((c.i>>16)&1u);   // RTNE
    return (u16)(r>>16);
}
__device__ __forceinline__ float sel4(float a0,float a1,float a2,float a3,int s){
    return s==0?a0:(s==1?a1:(s==2?a2:a3));
}

// ---- bf16 weight arena in d_ws: 16x32 wave-tiles, element offsets ----
// swz(n,k) = ((n>>4)*(K>>5) + (k>>5))*512 + (n&15)*32 + (k&31)
#define WP_OFF   0
#define WT_OFF   36864
#define INW_OFF  73728
#define OUTW_OFF 184320
#define FW1_OFF  221184
#define FW2_OFF  294912
#define CW1_OFF  368640
#define FPW_OFF  405504
#define W_TOTAL  430080            // elements; 860160 bytes

__global__ __launch_bounds__(256)
void cvt_weights(const float* __restrict__ Wp, const float* __restrict__ Wt,
                 const float* __restrict__ in_w, const float* __restrict__ out_w,
                 const float* __restrict__ fw1, const float* __restrict__ fw2,
                 const float* __restrict__ cw1, const float* __restrict__ fpw,
                 u16* __restrict__ ws)
{
    int idx = blockIdx.x * 256 + threadIdx.x;
    if (idx >= W_TOTAL) return;
    const float* src; int off; int K = 192;
    if      (idx < WT_OFF)   { src = Wp;   off = WP_OFF; }
    else if (idx < INW_OFF)  { src = Wt;   off = WT_OFF; }
    else if (idx < OUTW_OFF) { src = in_w; off = INW_OFF; }
    else if (idx < FW1_OFF)  { src = out_w;off = OUTW_OFF; }
    else if (idx < FW2_OFF)  { src = fw1;  off = FW1_OFF; }
    else if (idx < CW1_OFF)  { src = fw2;  off = FW2_OFF; K = 384; }
    else if (idx < FPW_OFF)  { src = cw1;  off = CW1_OFF; }
    else                     { src = fpw;  off = FPW_OFF; }
    int lin = idx - off;
    int n = lin / K, k = lin - n*K;
    int swz = ((n>>4)*(K>>5) + (k>>5))*512 + ((n&15)<<5) + (k&31);
    ws[off + swz] = f2b(src[lin]);
}

// A-frag: lane holds A[m = mt*16 + lane16][k = quad*8 + j] for k-step ks (k += 32*ks)
template<int KT, int MT>
__device__ __forceinline__ void load_afrags(short8 (&A)[MT][KT], const u16* base,
                                            int stride, int lane16, int quad)
{
    #pragma unroll
    for (int mt = 0; mt < MT; ++mt)
        #pragma unroll
        for (int ks = 0; ks < KT; ++ks)
            A[mt][ks] = *(const short8*)(base + (mt*16 + lane16)*stride + ks*32 + quad*8);
}

// C tile (M=MT*16, N=NTW*4 waves*16): B streamed from swizzled global bf16 tiles.
// C/D layout: row = quad*4 + reg, col = lane16 (m89-verified).
template<int KT, int MT, int NTW>
__device__ __forceinline__ void run_gemm(const short8 (&A)[MT][KT],
    const u16* __restrict__ wsb, const float* __restrict__ bias,
    u16* dst, float* dstf, int dstride,
    const u16* resid, int rstride, bool relu, int rmul, int roff,
    int wave, int lane16, int quad)
{
    #pragma unroll
    for (int i = 0; i < NTW; ++i) {
        int nt = wave + 4*i, n0 = nt*16;
        float4v c[MT];
        #pragma unroll
        for (int mt = 0; mt < MT; ++mt) c[mt] = (float4v){0.f,0.f,0.f,0.f};
        #pragma unroll
        for (int ks = 0; ks < KT; ++ks) {
            short8 b = *(const short8*)(wsb + (size_t)((nt*KT + ks)<<9) + (lane16<<5) + (quad<<3));
            #pragma unroll
            for (int mt = 0; mt < MT; ++mt)
                c[mt] = __builtin_amdgcn_mfma_f32_16x16x32_bf16(A[mt][ks], b, c[mt], 0,0,0);
        }
        float bv = bias[n0 + lane16];
        #pragma unroll
        for (int mt = 0; mt < MT; ++mt)
            #pragma unroll
            for (int ii = 0; ii < 4; ++ii) {
                int dr = (mt*16 + quad*4 + ii)*rmul + roff;
                float v = c[mt][ii] + bv;
                if (resid) v += b2f(resid[dr*rstride + n0 + lane16]);
                if (relu)  v = fmaxf(v, 0.f);
                if (dst) dst [dr*dstride + n0 + lane16] = f2b(v);
                else     dstf[dr*dstride + n0 + lane16] = v;
            }
    }
}

// ---- LDS arena (u16 elements), peak live = 12800 u16 = 25 KB ----
#define S1 200
#define SH 392
#define A_INP 0          // 16x200 inputs P   (dead after proj)
#define A_INT 3200       // 16x200 inputs T   (dead after proj)
#define A_SEQ 6400       // 32x200 seq        (x1 written in-place over it)
// satt_w: float[4][16][12] = 1536 u16 at arena[0] (over dead inputs, qkv phase)
#define A_CTX 0          // 32x200 ctx (over inputs/satt_w; dead after out-proj frags)
#define A_X1  6400       // 32x200 post-LN1 x1 (in-place over seq; dead after FFN1 frags)
#define A_H   0          // 32x392 = 12544 h (over ctx+x1, barrier-protected)
#define A_Z   0          // 16x200 z  (over dead h)
#define A_CH  3200       // 16x200 cls hidden
#define A_FPF 6400       // 16x128 f32 = 4096 u16
#define ARENA_U16 12800

__global__ __launch_bounds__(256, 4)
void fusion_mfma_kernel(
    const float* __restrict__ perc, const float* __restrict__ tech,
    const float* __restrict__ bp,   const float* __restrict__ bt,
    const float* __restrict__ in_b, const float* __restrict__ out_b,
    const float* __restrict__ fb1,  const float* __restrict__ fb2,
    const float* __restrict__ ln1g, const float* __restrict__ ln1b,
    const float* __restrict__ ln2g, const float* __restrict__ ln2b,
    const float* __restrict__ cb1,  const float* __restrict__ cw2,
    const float* __restrict__ cb2,  const float* __restrict__ fpb,
    const u16*   __restrict__ ws,
    float* __restrict__ out, int B)
{
    __shared__ __align__(16) u16 arena[ARENA_U16];
    __shared__ __align__(16) float satt[16][3][4];   // softmax probs [r][h][qt*2+kt]
    __shared__ float wavered[4][32][2];              // per-wave LN partials
    __shared__ float smu[32], srs[32], srn[16];

    const int tid = threadIdx.x;
    const int wave = tid >> 6, lane = tid & 63;
    const int lane16 = lane & 15, quad = lane >> 4;
    const int row0 = blockIdx.x * RPB;
    float* fpf = (float*)(arena + A_FPF);

    // ---- stage inputs -> bf16 LDS ----
    #pragma unroll
    for (int it = 0; it < 3; ++it) {
        int idx = it*256 + tid;           // 768 = 2 arrays * 16 rows * 24 groups-of-8
        int arr = idx >= 384 ? 1 : 0;
        int rem = arr ? idx - 384 : idx;
        int r = rem / 24, g = rem - r*24;
        const float* src = arr ? tech : perc;
        const float4* s4 = (const float4*)(src + (size_t)(row0 + r)*D + g*8);
        float4 lo = s4[0], hi = s4[1];
        short8 o;
        o[0]=(short)f2b(lo.x); o[1]=(short)f2b(lo.y); o[2]=(short)f2b(lo.z); o[3]=(short)f2b(lo.w);
        o[4]=(short)f2b(hi.x); o[5]=(short)f2b(hi.y); o[6]=(short)f2b(hi.z); o[7]=(short)f2b(hi.w);
        *(short8*)(arena + (arr ? A_INT : A_INP) + r*S1 + g*8) = o;
    }
    __syncthreads();

    // ---- proj_p / proj_t -> seq (tokens interleaved 2r / 2r+1) ----
    {
        short8 A1[1][6];
        load_afrags<6,1>(A1, arena + A_INP, S1, lane16, quad);
        run_gemm<6,1,3>(A1, ws + WP_OFF, bp, arena + A_SEQ, nullptr, S1,
                        nullptr, 0, false, 2, 0, wave, lane16, quad);
        load_afrags<6,1>(A1, arena + A_INT, S1, lane16, quad);
        run_gemm<6,1,3>(A1, ws + WT_OFF, bt, arena + A_SEQ, nullptr, S1,
                        nullptr, 0, false, 2, 1, wave, lane16, quad);
    }
    __syncthreads();

    // ---- qkv: per-head K_i -> Q_i -> scores, only satt_w touches LDS ----
    short8 A2[2][6];
    load_afrags<6,2>(A2, arena + A_SEQ, S1, lane16, quad);
    {
        float* satt_w = (float*)arena;   // [4][16][12] over dead inputs
        #pragma unroll
        for (int i = 0; i < 3; ++i) {    // head i (per-head: ck/cq only 16 regs live)
            int nt = wave + 4*i;
            float4v ck[2] = {(float4v){0,0,0,0},(float4v){0,0,0,0}};
            #pragma unroll
            for (int ks = 0; ks < 6; ++ks) {
                short8 b = *(const short8*)(ws + INW_OFF + 192*192 + ((nt*6+ks)<<9) + (lane16<<5) + (quad<<3));
                ck[0] = __builtin_amdgcn_mfma_f32_16x16x32_bf16(A2[0][ks], b, ck[0], 0,0,0);
                ck[1] = __builtin_amdgcn_mfma_f32_16x16x32_bf16(A2[1][ks], b, ck[1], 0,0,0);
            }
            float bvk = in_b[192 + nt*16 + lane16];
            float4v cq[2] = {(float4v){0,0,0,0},(float4v){0,0,0,0}};
            #pragma unroll
            for (int ks = 0; ks < 6; ++ks) {
                short8 b = *(const short8*)(ws + INW_OFF + ((nt*6+ks)<<9) + (lane16<<5) + (quad<<3));
                cq[0] = __builtin_amdgcn_mfma_f32_16x16x32_bf16(A2[0][ks], b, cq[0], 0,0,0);
                cq[1] = __builtin_amdgcn_mfma_f32_16x16x32_bf16(A2[1][ks], b, cq[1], 0,0,0);
            }
            float bvq = in_b[nt*16 + lane16];
            float sc[2][2][4];           // [mt][p][qt*2+kt], compile-time indexed
            #pragma unroll
            for (int mt = 0; mt < 2; ++mt)
                #pragma unroll
                for (int p = 0; p < 2; ++p) {
                    float q0 = cq[mt][2*p] + bvq, q1 = cq[mt][2*p+1] + bvq;
                    float k0 = ck[mt][2*p] + bvk, k1 = ck[mt][2*p+1] + bvk;
                    sc[mt][p][0] = q0*k0; sc[mt][p][1] = q0*k1;
                    sc[mt][p][2] = q1*k0; sc[mt][p][3] = q1*k1;
                }
            #pragma unroll
            for (int mt = 0; mt < 2; ++mt)
                #pragma unroll
                for (int p = 0; p < 2; ++p)
                    #pragma unroll
                    for (int c = 0; c < 4; ++c) {
                        float v = sc[mt][p][c];
                        v += __shfl_xor(v, 1); v += __shfl_xor(v, 2);
                        v += __shfl_xor(v, 4); v += __shfl_xor(v, 8);
                        sc[mt][p][c] = v;
                    }
            if ((lane16 >> 2) == i) {
                int c = lane16 & 3;
                #pragma unroll
                for (int mt = 0; mt < 2; ++mt)
                    #pragma unroll
                    for (int p = 0; p < 2; ++p) {
                        float vv = sel4(sc[mt][p][0], sc[mt][p][1], sc[mt][p][2], sc[mt][p][3], c);
                        satt_w[(wave*16 + (2*quad + p + 8*mt))*12 + i*4 + c] = vv;
                    }
            }
        }
    }
    __syncthreads();

    // ---- softmax finalize (96 threads) ----
    if (tid < 96) {
        const float* satt_w = (const float*)arena;
        int r = tid / 6, rem = tid - r*6;
        int h = rem >> 1, qt = rem & 1;
        float s0 = 0.f, s1 = 0.f;
        #pragma unroll
        for (int w = 0; w < 4; ++w) {
            s0 += satt_w[(w*16 + r)*12 + h*4 + qt*2 + 0];
            s1 += satt_w[(w*16 + r)*12 + h*4 + qt*2 + 1];
        }
        s0 *= 0.125f; s1 *= 0.125f;
        float m = fmaxf(s0, s1);
        float e0 = expf(s0 - m), e1 = expf(s1 - m);
        float inv = 1.f / (e0 + e1);
        satt[r][h][qt*2 + 0] = e0 * inv;
        satt[r][h][qt*2 + 1] = e1 * inv;
    }
    __syncthreads();

    // ---- V-GEMM fused with ctx (writes ctx over dead inputs/satt_w) ----
    #pragma unroll
    for (int i = 0; i < 3; ++i) {
        int nt = wave + 4*i, col = nt*16 + lane16;
        float4v cv[2] = {(float4v){0,0,0,0},(float4v){0,0,0,0}};
        #pragma unroll
        for (int ks = 0; ks < 6; ++ks) {
            short8 b = *(const short8*)(ws + INW_OFF + 384*192 + ((nt*6+ks)<<9) + (lane16<<5) + (quad<<3));
            cv[0] = __builtin_amdgcn_mfma_f32_16x16x32_bf16(A2[0][ks], b, cv[0], 0,0,0);
            cv[1] = __builtin_amdgcn_mfma_f32_16x16x32_bf16(A2[1][ks], b, cv[1], 0,0,0);
        }
        float bv = in_b[384 + col];
        #pragma unroll
        for (int mt = 0; mt < 2; ++mt)
            #pragma unroll
            for (int p = 0; p < 2; ++p) {
                float v0 = cv[mt][2*p] + bv, v1 = cv[mt][2*p+1] + bv;
                int r = 2*quad + p + 8*mt;
                float4 pa = *(const float4*)&satt[r][i][0];
                arena[A_CTX + (2*r    )*S1 + col] = f2b(pa.x*v0 + pa.y*v1);
                arena[A_CTX + (2*r + 1)*S1 + col] = f2b(pa.z*v0 + pa.w*v1);
            }
    }
    __syncthreads();

    // ---- out-proj + residual(seq) -> x1 kept in REGS; LN1 partials fused ----
    float4v x1r[3][2];
    {
        short8 Ac[2][6];
        load_afrags<6,2>(Ac, arena + A_CTX, S1, lane16, quad);
        #pragma unroll
        for (int i = 0; i < 3; ++i) {
            int nt = wave + 4*i, col = nt*16 + lane16;
            x1r[i][0] = (float4v){0,0,0,0}; x1r[i][1] = (float4v){0,0,0,0};
            #pragma unroll
            for (int ks = 0; ks < 6; ++ks) {
                short8 b = *(const short8*)(ws + OUTW_OFF + ((nt*6+ks)<<9) + (lane16<<5) + (quad<<3));
                x1r[i][0] = __builtin_amdgcn_mfma_f32_16x16x32_bf16(Ac[0][ks], b, x1r[i][0], 0,0,0);
                x1r[i][1] = __builtin_amdgcn_mfma_f32_16x16x32_bf16(Ac[1][ks], b, x1r[i][1], 0,0,0);
            }
            float bv = out_b[col];
            #pragma unroll
            for (int mt = 0; mt < 2; ++mt)
                #pragma unroll
                for (int ii = 0; ii < 4; ++ii) {
                    int row = quad*4 + ii + 16*mt;
                    x1r[i][mt][ii] += bv + b2f(arena[A_SEQ + row*S1 + col]);
                }
        }
        // LN1 row partials (8 rows/thread over its 3 cols) -> butterfly -> wavered
        float sr[2][4], s2r[2][4];
        #pragma unroll
        for (int mt = 0; mt < 2; ++mt)
            #pragma unroll
            for (int ii = 0; ii < 4; ++ii) {
                float a0 = x1r[0][mt][ii], a1 = x1r[1][mt][ii], a2 = x1r[2][mt][ii];
                float s = a0 + a1 + a2;
                float s2 = a0*a0 + a1*a1 + a2*a2;
                s  += __shfl_xor(s, 1);  s  += __shfl_xor(s, 2);
                s  += __shfl_xor(s, 4);  s  += __shfl_xor(s, 8);
                s2 += __shfl_xor(s2, 1); s2 += __shfl_xor(s2, 2);
                s2 += __shfl_xor(s2, 4); s2 += __shfl_xor(s2, 8);
                sr[mt][ii] = s; s2r[mt][ii] = s2;
            }
        int l = lane16;
        float rowlo = sel4(sr[0][0], sr[0][1], sr[0][2], sr[0][3], l & 3);
        float rowhi = sel4(sr[1][0], sr[1][1], sr[1][2], sr[1][3], l & 3);
        float row2lo = sel4(s2r[0][0], s2r[0][1], s2r[0][2], s2r[0][3], l & 3);
        float row2hi = sel4(s2r[1][0], s2r[1][1], s2r[1][2], s2r[1][3], l & 3);
        float sv = (l & 4) ? rowhi : rowlo;
        float s2v = (l & 4) ? row2hi : row2lo;
        float val = (l & 8) ? s2v : sv;
        wavered[wave][quad*4 + (l & 3) + 16*((l >> 2) & 1)][l >> 3] = val;
    }
    __syncthreads();
    if (tid < 32) {
        float s = 0.f, s2 = 0.f;
        #pragma unroll
        for (int w = 0; w < 4; ++w) { s += wavered[w][tid][0]; s2 += wavered[w][tid][1]; }
        float mu = s * (1.f/192.f);
        float var = s2 * (1.f/192.f) - mu*mu;
        smu[tid] = mu; srs[tid] = rsqrtf(var + 1e-5f);
    }
    __syncthreads();

    // ---- LN1 apply to regs + write post-LN x1 to LDS (for FFN1 frags) ----
    #pragma unroll
    for (int i = 0; i < 3; ++i) {
        int col = (wave + 4*i)*16 + lane16;
        float g = ln1g[col], bb = ln1b[col];
        #pragma unroll
        for (int mt = 0; mt < 2; ++mt)
            #pragma unroll
            for (int ii = 0; ii < 4; ++ii) {
                int row = quad*4 + ii + 16*mt;
                float x = (x1r[i][mt][ii] - smu[row]) * srs[row] * g + bb;
                x1r[i][mt][ii] = x;
                arena[A_X1 + row*S1 + col] = f2b(x);
            }
    }
    __syncthreads();

    // ---- FFN1 (relu) -> h; h overwrites ctx+x1 (frags loaded, then barrier) ----
    {
        short8 Ax[2][6];
        load_afrags<6,2>(Ax, arena + A_X1, S1, lane16, quad);
        __syncthreads();            // all frag loads done before h overwrites x1
        run_gemm<6,2,6>(Ax, ws + FW1_OFF, fb1, arena + A_H, nullptr, SH,
                        nullptr, 0, true, 1, 0, wave, lane16, quad);
    }
    __syncthreads();

    // ---- FFN2 (K=384) + reg-resid -> x2 in REGS; LN2 partials fused ----
    {
        float4v c2[3][2];
        #pragma unroll
        for (int i = 0; i < 3; ++i) { c2[i][0] = (float4v){0,0,0,0}; c2[i][1] = (float4v){0,0,0,0}; }
        #pragma unroll
        for (int kc = 0; kc < 2; ++kc) {
            short8 Af[2][6];
            load_afrags<6,2>(Af, arena + A_H + kc*192, SH, lane16, quad);
            #pragma unroll
            for (int i = 0; i < 3; ++i) {
                int nt = wave + 4*i;
                #pragma unroll
                for (int ks = 0; ks < 6; ++ks) {
                    short8 b = *(const short8*)(ws + FW2_OFF + ((nt*12 + kc*6 + ks)<<9) + (lane16<<5) + (quad<<3));
                    c2[i][0] = __builtin_amdgcn_mfma_f32_16x16x32_bf16(Af[0][ks], b, c2[i][0], 0,0,0);
                    c2[i][1] = __builtin_amdgcn_mfma_f32_16x16x32_bf16(Af[1][ks], b, c2[i][1], 0,0,0);
                }
            }
        }
        #pragma unroll
        for (int i = 0; i < 3; ++i) {
            float bv = fb2[(wave + 4*i)*16 + lane16];
            #pragma unroll
            for (int mt = 0; mt < 2; ++mt)
                #pragma unroll
                for (int ii = 0; ii < 4; ++ii)
                    c2[i][mt][ii] += bv + x1r[i][mt][ii];
        }
        // LN2 partials
        float sr[2][4], s2r[2][4];
        #pragma unroll
        for (int mt = 0; mt < 2; ++mt)
            #pragma unroll
            for (int ii = 0; ii < 4; ++ii) {
                float a0 = c2[0][mt][ii], a1 = c2[1][mt][ii], a2 = c2[2][mt][ii];
                float s = a0 + a1 + a2;
                float s2 = a0*a0 + a1*a1 + a2*a2;
                s  += __shfl_xor(s, 1);  s  += __shfl_xor(s, 2);
                s  += __shfl_xor(s, 4);  s  += __shfl_xor(s, 8);
                s2 += __shfl_xor(s2, 1); s2 += __shfl_xor(s2, 2);
                s2 += __shfl_xor(s2, 4); s2 += __shfl_xor(s2, 8);
                sr[mt][ii] = s; s2r[mt][ii] = s2;
            }
        int l = lane16;
        float rowlo = sel4(sr[0][0], sr[0][1], sr[0][2], sr[0][3], l & 3);
        float rowhi = sel4(sr[1][0], sr[1][1], sr[1][2], sr[1][3], l & 3);
        float row2lo = sel4(s2r[0][0], s2r[0][1], s2r[0][2], s2r[0][3], l & 3);
        float row2hi = sel4(s2r[1][0], s2r[1][1], s2r[1][2], s2r[1][3], l & 3);
        float sv = (l & 4) ? rowhi : rowlo;
        float s2v = (l & 4) ? row2hi : row2lo;
        float val = (l & 8) ? s2v : sv;
        wavered[wave][quad*4 + (l & 3) + 16*((l >> 2) & 1)][l >> 3] = val;
        __syncthreads();
        if (tid < 32) {
            float s = 0.f, s2 = 0.f;
            #pragma unroll
            for (int w = 0; w < 4; ++w) { s += wavered[w][tid][0]; s2 += wavered[w][tid][1]; }
            float mu = s * (1.f/192.f);
            float var = s2 * (1.f/192.f) - mu*mu;
            smu[tid] = mu; srs[tid] = rsqrtf(var + 1e-5f);
        }
        __syncthreads();
        // ---- LN2 apply + token-mean in-thread -> z (over dead h) ----
        #pragma unroll
        for (int i = 0; i < 3; ++i) {
            int col = (wave + 4*i)*16 + lane16;
            float g = ln2g[col], bb = ln2b[col];
            #pragma unroll
            for (int mt = 0; mt < 2; ++mt)
                #pragma unroll
                for (int p = 0; p < 2; ++p) {
                    int r = 2*quad + p + 8*mt;
                    float n0v = (c2[i][mt][2*p]   - smu[2*r  ]) * srs[2*r  ] * g + bb;
                    float n1v = (c2[i][mt][2*p+1] - smu[2*r+1]) * srs[2*r+1] * g + bb;
                    arena[A_Z + r*S1 + col] = f2b(0.5f*(n0v + n1v));
                }
        }
    }
    __syncthreads();

    // ---- heads: cls1 (relu -> ch), fingerprint (f32 -> fpf) ----
    {
        short8 A1[1][6];
        load_afrags<6,1>(A1, arena + A_Z, S1, lane16, quad);
        run_gemm<6,1,3>(A1, ws + CW1_OFF, cb1, arena + A_CH, nullptr, S1,
                        nullptr, 0, true, 1, 0, wave, lane16, quad);
        run_gemm<6,1,2>(A1, ws + FPW_OFF, fpb, nullptr, fpf, 128,
                        nullptr, 0, false, 1, 0, wave, lane16, quad);
    }
    __syncthreads();

    // ---- cls2+sigmoid (waves 0-2) || fp-norm partials (wave 3) ----
    if (tid < 192) {
        int g4 = tid >> 2, sub = tid & 3;
        int r = g4 / 3, cc = g4 - r*3;
        const float* w = cw2 + (size_t)cc * D + sub*48;
        const u16* hr = arena + A_CH + r*S1 + sub*48;
        float a = 0.f;
        #pragma unroll
        for (int i = 0; i < 6; ++i) {
            short8 hv = *(const short8*)(hr + i*8);
            float4 w0 = ((const float4*)w)[2*i], w1 = ((const float4*)w)[2*i+1];
            float wv[8] = {w0.x,w0.y,w0.z,w0.w,w1.x,w1.y,w1.z,w1.w};
            #pragma unroll
            for (int j = 0; j < 8; ++j) a += wv[j] * b2f((u16)hv[j]);
        }
        a += __shfl_xor(a, 1); a += __shfl_xor(a, 2);
        if (sub == 0) {
            a += cb2[cc];
            out[(size_t)cc * B + (size_t)(row0 + r)] = 1.f / (1.f + expf(-a));
        }
    } else {
        int t = tid - 192;               // 64 threads: 16 rows x 4-lane split
        int r = t >> 2, sub = t & 3;
        const float4* fp4 = (const float4*)(fpf + r*128 + sub*32);
        float s2 = 0.f;
        #pragma unroll
        for (int i = 0; i < 8; ++i) {
            float4 v = fp4[i];
            s2 += v.x*v.x + v.y*v.y + v.z*v.z + v.w*v.w;
        }
        s2 += __shfl_xor(s2, 1); s2 += __shfl_xor(s2, 2);
        if (sub == 0) srn[r] = 1.f / fmaxf(sqrtf(s2), 1e-12f);
    }
    __syncthreads();

    // ---- fingerprint writeout (float4) ----
    #pragma unroll
    for (int it = 0; it < 2; ++it) {
        int idx = it*256 + tid;          // 512 = 16 r * 32 float4
        int r = idx >> 5, c = idx & 31;
        float4 v = ((const float4*)(fpf + r*128))[c];
        float sc = srn[r];
        float4 o; o.x = v.x*sc; o.y = v.y*sc; o.z = v.z*sc; o.w = v.w*sc;
        ((float4*)(out + (size_t)3*B + (size_t)(row0 + r)*128))[c] = o;
    }
}

extern "C" void kernel_launch(void* const* d_in, const int* in_sizes, int n_in,
                              void* d_out, int out_size, void* d_ws, size_t ws_size,
                              hipStream_t stream) {
    if (ws_size < (size_t)W_TOTAL * 2) return;   // visible failure -> ws too small

    const float* perc = (const float*)d_in[0];
    const float* tech = (const float*)d_in[1];
    const float* Wp   = (const float*)d_in[2];
    const float* bp   = (const float*)d_in[3];
    const float* Wt   = (const float*)d_in[4];
    const float* bt   = (const float*)d_in[5];
    const float* in_w = (const float*)d_in[6];
    const float* in_b = (const float*)d_in[7];
    const float* ow   = (const float*)d_in[8];
    const float* ob   = (const float*)d_in[9];
    const float* fw1  = (const float*)d_in[10];
    const float* fb1  = (const float*)d_in[11];
    const float* fw2  = (const float*)d_in[12];
    const float* fb2  = (const float*)d_in[13];
    const float* ln1g = (const float*)d_in[14];
    const float* ln1b = (const float*)d_in[15];
    const float* ln2g = (const float*)d_in[16];
    const float* ln2b = (const float*)d_in[17];
    const float* cw1  = (const float*)d_in[18];
    const float* cb1  = (const float*)d_in[19];
    const float* cw2  = (const float*)d_in[20];
    const float* cb2  = (const float*)d_in[21];
    const float* fpw  = (const float*)d_in[22];
    const float* fpb  = (const float*)d_in[23];

    u16* ws = (u16*)d_ws;
    int B = in_sizes[0] / D;

    hipLaunchKernelGGL(cvt_weights, dim3((W_TOTAL + 255)/256), dim3(256), 0, stream,
                       Wp, Wt, in_w, ow, fw1, fw2, cw1, fpw, ws);

    hipLaunchKernelGGL(fusion_mfma_kernel, dim3(B / RPB), dim3(256), 0, stream,
                       perc, tech, bp, bt, in_b, ob, fb1, fb2,
                       ln1g, ln1b, ln2g, ln2b, cb1, cw2, cb2, fpb,
                       ws, (float*)d_out, B);
}

// Round 5
// 401.279 us; speedup vs baseline: 1.2878x; 1.0510x over previous
//
#include <hip/hip_runtime.h>
#include <hip/hip_bf16.h>
#include <math.h>

#define D 192
#define RPB 16                       // rows per block -> M = 32 tokens
typedef unsigned short u16;
typedef __attribute__((ext_vector_type(8))) short short8;   // 8 bf16 (4 VGPRs)
typedef __attribute__((ext_vector_type(4))) float float4v;  // MFMA C/D

__device__ __forceinline__ float b2f(u16 u){ union{unsigned i; float f;}c; c.i=(unsigned)u<<16; return c.f; }
__device__ __forceinline__ u16  f2b(float f){
    union{float f; unsigned i;}c; c.f=f;
    unsigned r = c.i + 0x7FFFu + ((c.i>>16)&1u);   // RTNE
    return (u16)(r>>16);
}
__device__ __forceinline__ float sel4(float a0,float a1,float a2,float a3,int s){
    return s==0?a0:(s==1?a1:(s==2?a2:a3));
}

// ---- bf16 weight arena in d_ws: 16x32 wave-tiles, element offsets ----
// swz(n,k) = ((n>>4)*(K>>5) + (k>>5))*512 + (n&15)*32 + (k&31)
#define WP_OFF   0
#define WT_OFF   36864
#define INW_OFF  73728
#define OUTW_OFF 184320
#define FW1_OFF  221184
#define FW2_OFF  294912
#define CW1_OFF  368640
#define FPW_OFF  405504
#define W_TOTAL  430080            // elements; 860160 bytes

__global__ __launch_bounds__(256)
void cvt_weights(const float* __restrict__ Wp, const float* __restrict__ Wt,
                 const float* __restrict__ in_w, const float* __restrict__ out_w,
                 const float* __restrict__ fw1, const float* __restrict__ fw2,
                 const float* __restrict__ cw1, const float* __restrict__ fpw,
                 u16* __restrict__ ws)
{
    int idx = blockIdx.x * 256 + threadIdx.x;
    if (idx >= W_TOTAL) return;
    const float* src; int off; int K = 192;
    if      (idx < WT_OFF)   { src = Wp;   off = WP_OFF; }
    else if (idx < INW_OFF)  { src = Wt;   off = WT_OFF; }
    else if (idx < OUTW_OFF) { src = in_w; off = INW_OFF; }
    else if (idx < FW1_OFF)  { src = out_w;off = OUTW_OFF; }
    else if (idx < FW2_OFF)  { src = fw1;  off = FW1_OFF; }
    else if (idx < CW1_OFF)  { src = fw2;  off = FW2_OFF; K = 384; }
    else if (idx < FPW_OFF)  { src = cw1;  off = CW1_OFF; }
    else                     { src = fpw;  off = FPW_OFF; }
    int lin = idx - off;
    int n = lin / K, k = lin - n*K;
    int swz = ((n>>4)*(K>>5) + (k>>5))*512 + ((n&15)<<5) + (k&31);
    ws[off + swz] = f2b(src[lin]);
}

// A-frag: lane holds A[m = mt*16 + lane16][k = quad*8 + j] for k-step ks (k += 32*ks)
template<int KT, int MT>
__device__ __forceinline__ void load_afrags(short8 (&A)[MT][KT], const u16* base,
                                            int stride, int lane16, int quad)
{
    #pragma unroll
    for (int mt = 0; mt < MT; ++mt)
        #pragma unroll
        for (int ks = 0; ks < KT; ++ks)
            A[mt][ks] = *(const short8*)(base + (mt*16 + lane16)*stride + ks*32 + quad*8);
}

// C tile (M=MT*16, N=NTW*4 waves*16): B streamed from swizzled global bf16 tiles.
// C/D layout: row = quad*4 + reg, col = lane16 (m89-verified).
template<int KT, int MT, int NTW>
__device__ __forceinline__ void run_gemm(const short8 (&A)[MT][KT],
    const u16* __restrict__ wsb, const float* __restrict__ bias,
    u16* dst, float* dstf, int dstride,
    const u16* resid, int rstride, bool relu, int rmul, int roff,
    int wave, int lane16, int quad)
{
    #pragma unroll
    for (int i = 0; i < NTW; ++i) {
        int nt = wave + 4*i, n0 = nt*16;
        float4v c[MT];
        #pragma unroll
        for (int mt = 0; mt < MT; ++mt) c[mt] = (float4v){0.f,0.f,0.f,0.f};
        #pragma unroll
        for (int ks = 0; ks < KT; ++ks) {
            short8 b = *(const short8*)(wsb + (size_t)((nt*KT + ks)<<9) + (lane16<<5) + (quad<<3));
            #pragma unroll
            for (int mt = 0; mt < MT; ++mt)
                c[mt] = __builtin_amdgcn_mfma_f32_16x16x32_bf16(A[mt][ks], b, c[mt], 0,0,0);
        }
        float bv = bias[n0 + lane16];
        #pragma unroll
        for (int mt = 0; mt < MT; ++mt)
            #pragma unroll
            for (int ii = 0; ii < 4; ++ii) {
                int dr = (mt*16 + quad*4 + ii)*rmul + roff;
                float v = c[mt][ii] + bv;
                if (resid) v += b2f(resid[dr*rstride + n0 + lane16]);
                if (relu)  v = fmaxf(v, 0.f);
                if (dst) dst [dr*dstride + n0 + lane16] = f2b(v);
                else     dstf[dr*dstride + n0 + lane16] = v;
            }
    }
}

// ---- LDS arena (u16 elements), peak live = 18944 u16 = 37 KB ----
// x1 (32x200 @12544) coexists with h (32x392 @0) so FFN2 can read the residual.
#define S1 200
#define SH 392
#define A_STG_P 0        // 16x200 staging P (dead after proj)
#define A_STG_T 3200     // 16x200 staging T (dead after proj)
#define A_SEQ 12544      // 32x200 seq; pre-LN x1 written IN-PLACE over it
// satt_w: float[4][16][12] = 1536 u16 at arena[0] (over dead staging, qkv phase)
#define A_CTX 0          // 32x200 ctx (over staging/satt_w; dead after out-proj frags)
#define A_X1  12544      // 32x200 x1 (in-place over seq; live through FFN2)
#define A_H   0          // 32x392 = 12544 h (over ctx; no x1 overlap)
#define A_Z   0          // 16x200 z  (over dead h)
#define A_CH  3200       // 16x200 cls hidden
#define A_FPF 6400       // 16x128 f32 = 4096 u16 (over dead h)
#define ARENA_U16 18944

__global__ __launch_bounds__(256, 4)
void fusion_mfma_kernel(
    const float* __restrict__ perc, const float* __restrict__ tech,
    const float* __restrict__ bp,   const float* __restrict__ bt,
    const float* __restrict__ in_b, const float* __restrict__ out_b,
    const float* __restrict__ fb1,  const float* __restrict__ fb2,
    const float* __restrict__ ln1g, const float* __restrict__ ln1b,
    const float* __restrict__ ln2g, const float* __restrict__ ln2b,
    const float* __restrict__ cb1,  const float* __restrict__ cw2,
    const float* __restrict__ cb2,  const float* __restrict__ fpb,
    const u16*   __restrict__ ws,
    float* __restrict__ out, int B)
{
    __shared__ __align__(16) u16 arena[ARENA_U16];
    __shared__ __align__(16) float satt[16][3][4];   // softmax probs [r][h][qt*2+kt]
    __shared__ float wavered[4][32][2];              // per-wave LN partials
    __shared__ float smu[32], srs[32], srn[16];

    const int tid = threadIdx.x;
    const int wave = tid >> 6, lane = tid & 63;
    const int lane16 = lane & 15, quad = lane >> 4;
    const int row0 = blockIdx.x * RPB;
    float* fpf = (float*)(arena + A_FPF);

    // ---- stage inputs -> bf16 LDS ----
    #pragma unroll
    for (int it = 0; it < 3; ++it) {
        int idx = it*256 + tid;           // 768 = 2 arrays * 16 rows * 24 groups-of-8
        int arr = idx >= 384 ? 1 : 0;
        int rem = arr ? idx - 384 : idx;
        int r = rem / 24, g = rem - r*24;
        const float* src = arr ? tech : perc;
        const float4* s4 = (const float4*)(src + (size_t)(row0 + r)*D + g*8);
        float4 lo = s4[0], hi = s4[1];
        short8 o;
        o[0]=(short)f2b(lo.x); o[1]=(short)f2b(lo.y); o[2]=(short)f2b(lo.z); o[3]=(short)f2b(lo.w);
        o[4]=(short)f2b(hi.x); o[5]=(short)f2b(hi.y); o[6]=(short)f2b(hi.z); o[7]=(short)f2b(hi.w);
        *(short8*)(arena + (arr ? A_STG_T : A_STG_P) + r*S1 + g*8) = o;
    }
    __syncthreads();

    // ---- proj_p / proj_t -> seq (tokens interleaved 2r / 2r+1) ----
    {
        short8 A1[1][6];
        load_afrags<6,1>(A1, arena + A_STG_P, S1, lane16, quad);
        run_gemm<6,1,3>(A1, ws + WP_OFF, bp, arena + A_SEQ, nullptr, S1,
                        nullptr, 0, false, 2, 0, wave, lane16, quad);
        load_afrags<6,1>(A1, arena + A_STG_T, S1, lane16, quad);
        run_gemm<6,1,3>(A1, ws + WT_OFF, bt, arena + A_SEQ, nullptr, S1,
                        nullptr, 0, false, 2, 1, wave, lane16, quad);
    }
    __syncthreads();

    // ---- qkv: per-head K_i -> Q_i -> scores, only satt_w touches LDS ----
    short8 A2[2][6];
    load_afrags<6,2>(A2, arena + A_SEQ, S1, lane16, quad);
    {
        float* satt_w = (float*)arena;   // [4][16][12] over dead staging
        #pragma unroll
        for (int i = 0; i < 3; ++i) {    // head i (per-head: ck/cq only 16 regs live)
            int nt = wave + 4*i;
            float4v ck[2] = {(float4v){0,0,0,0},(float4v){0,0,0,0}};
            #pragma unroll
            for (int ks = 0; ks < 6; ++ks) {
                short8 b = *(const short8*)(ws + INW_OFF + 192*192 + ((nt*6+ks)<<9) + (lane16<<5) + (quad<<3));
                ck[0] = __builtin_amdgcn_mfma_f32_16x16x32_bf16(A2[0][ks], b, ck[0], 0,0,0);
                ck[1] = __builtin_amdgcn_mfma_f32_16x16x32_bf16(A2[1][ks], b, ck[1], 0,0,0);
            }
            float bvk = in_b[192 + nt*16 + lane16];
            float4v cq[2] = {(float4v){0,0,0,0},(float4v){0,0,0,0}};
            #pragma unroll
            for (int ks = 0; ks < 6; ++ks) {
                short8 b = *(const short8*)(ws + INW_OFF + ((nt*6+ks)<<9) + (lane16<<5) + (quad<<3));
                cq[0] = __builtin_amdgcn_mfma_f32_16x16x32_bf16(A2[0][ks], b, cq[0], 0,0,0);
                cq[1] = __builtin_amdgcn_mfma_f32_16x16x32_bf16(A2[1][ks], b, cq[1], 0,0,0);
            }
            float bvq = in_b[nt*16 + lane16];
            float sc[2][2][4];           // [mt][p][qt*2+kt], compile-time indexed
            #pragma unroll
            for (int mt = 0; mt < 2; ++mt)
                #pragma unroll
                for (int p = 0; p < 2; ++p) {
                    float q0 = cq[mt][2*p] + bvq, q1 = cq[mt][2*p+1] + bvq;
                    float k0 = ck[mt][2*p] + bvk, k1 = ck[mt][2*p+1] + bvk;
                    sc[mt][p][0] = q0*k0; sc[mt][p][1] = q0*k1;
                    sc[mt][p][2] = q1*k0; sc[mt][p][3] = q1*k1;
                }
            #pragma unroll
            for (int mt = 0; mt < 2; ++mt)
                #pragma unroll
                for (int p = 0; p < 2; ++p)
                    #pragma unroll
                    for (int c = 0; c < 4; ++c) {
                        float v = sc[mt][p][c];
                        v += __shfl_xor(v, 1); v += __shfl_xor(v, 2);
                        v += __shfl_xor(v, 4); v += __shfl_xor(v, 8);
                        sc[mt][p][c] = v;
                    }
            if ((lane16 >> 2) == i) {
                int c = lane16 & 3;
                #pragma unroll
                for (int mt = 0; mt < 2; ++mt)
                    #pragma unroll
                    for (int p = 0; p < 2; ++p) {
                        float vv = sel4(sc[mt][p][0], sc[mt][p][1], sc[mt][p][2], sc[mt][p][3], c);
                        satt_w[(wave*16 + (2*quad + p + 8*mt))*12 + i*4 + c] = vv;
                    }
            }
        }
    }
    __syncthreads();

    // ---- softmax finalize (96 threads) ----
    if (tid < 96) {
        const float* satt_w = (const float*)arena;
        int r = tid / 6, rem = tid - r*6;
        int h = rem >> 1, qt = rem & 1;
        float s0 = 0.f, s1 = 0.f;
        #pragma unroll
        for (int w = 0; w < 4; ++w) {
            s0 += satt_w[(w*16 + r)*12 + h*4 + qt*2 + 0];
            s1 += satt_w[(w*16 + r)*12 + h*4 + qt*2 + 1];
        }
        s0 *= 0.125f; s1 *= 0.125f;
        float m = fmaxf(s0, s1);
        float e0 = expf(s0 - m), e1 = expf(s1 - m);
        float inv = 1.f / (e0 + e1);
        satt[r][h][qt*2 + 0] = e0 * inv;
        satt[r][h][qt*2 + 1] = e1 * inv;
    }
    __syncthreads();

    // ---- V-GEMM fused with ctx (writes ctx over dead staging/satt_w) ----
    #pragma unroll
    for (int i = 0; i < 3; ++i) {
        int nt = wave + 4*i, col = nt*16 + lane16;
        float4v cv[2] = {(float4v){0,0,0,0},(float4v){0,0,0,0}};
        #pragma unroll
        for (int ks = 0; ks < 6; ++ks) {
            short8 b = *(const short8*)(ws + INW_OFF + 384*192 + ((nt*6+ks)<<9) + (lane16<<5) + (quad<<3));
            cv[0] = __builtin_amdgcn_mfma_f32_16x16x32_bf16(A2[0][ks], b, cv[0], 0,0,0);
            cv[1] = __builtin_amdgcn_mfma_f32_16x16x32_bf16(A2[1][ks], b, cv[1], 0,0,0);
        }
        float bv = in_b[384 + col];
        #pragma unroll
        for (int mt = 0; mt < 2; ++mt)
            #pragma unroll
            for (int p = 0; p < 2; ++p) {
                float v0 = cv[mt][2*p] + bv, v1 = cv[mt][2*p+1] + bv;
                int r = 2*quad + p + 8*mt;
                float4 pa = *(const float4*)&satt[r][i][0];
                arena[A_CTX + (2*r    )*S1 + col] = f2b(pa.x*v0 + pa.y*v1);
                arena[A_CTX + (2*r + 1)*S1 + col] = f2b(pa.z*v0 + pa.w*v1);
            }
    }
    __syncthreads();

    // ---- out-proj + residual(seq) -> pre-LN x1 IN LDS (in-place over seq);
    //      LN1 partials fused (no persistent x1 registers) ----
    {
        short8 Ac[2][6];
        load_afrags<6,2>(Ac, arena + A_CTX, S1, lane16, quad);
        float sa[2][4], s2a[2][4];
        #pragma unroll
        for (int mt = 0; mt < 2; ++mt)
            #pragma unroll
            for (int ii = 0; ii < 4; ++ii) { sa[mt][ii] = 0.f; s2a[mt][ii] = 0.f; }
        #pragma unroll
        for (int i = 0; i < 3; ++i) {
            int nt = wave + 4*i, col = nt*16 + lane16;
            float4v c[2] = {(float4v){0,0,0,0},(float4v){0,0,0,0}};
            #pragma unroll
            for (int ks = 0; ks < 6; ++ks) {
                short8 b = *(const short8*)(ws + OUTW_OFF + ((nt*6+ks)<<9) + (lane16<<5) + (quad<<3));
                c[0] = __builtin_amdgcn_mfma_f32_16x16x32_bf16(Ac[0][ks], b, c[0], 0,0,0);
                c[1] = __builtin_amdgcn_mfma_f32_16x16x32_bf16(Ac[1][ks], b, c[1], 0,0,0);
            }
            float bv = out_b[col];
            #pragma unroll
            for (int mt = 0; mt < 2; ++mt)
                #pragma unroll
                for (int ii = 0; ii < 4; ++ii) {
                    int row = quad*4 + ii + 16*mt;
                    float v = c[mt][ii] + bv + b2f(arena[A_SEQ + row*S1 + col]);
                    arena[A_X1 + row*S1 + col] = f2b(v);   // same-thread RMW, safe
                    sa[mt][ii] += v; s2a[mt][ii] += v*v;
                }
        }
        // butterfly over lane16 -> wavered
        #pragma unroll
        for (int mt = 0; mt < 2; ++mt)
            #pragma unroll
            for (int ii = 0; ii < 4; ++ii) {
                float s = sa[mt][ii], s2 = s2a[mt][ii];
                s  += __shfl_xor(s, 1);  s  += __shfl_xor(s, 2);
                s  += __shfl_xor(s, 4);  s  += __shfl_xor(s, 8);
                s2 += __shfl_xor(s2, 1); s2 += __shfl_xor(s2, 2);
                s2 += __shfl_xor(s2, 4); s2 += __shfl_xor(s2, 8);
                sa[mt][ii] = s; s2a[mt][ii] = s2;
            }
        int l = lane16;
        float rowlo = sel4(sa[0][0], sa[0][1], sa[0][2], sa[0][3], l & 3);
        float rowhi = sel4(sa[1][0], sa[1][1], sa[1][2], sa[1][3], l & 3);
        float row2lo = sel4(s2a[0][0], s2a[0][1], s2a[0][2], s2a[0][3], l & 3);
        float row2hi = sel4(s2a[1][0], s2a[1][1], s2a[1][2], s2a[1][3], l & 3);
        float sv = (l & 4) ? rowhi : rowlo;
        float s2v = (l & 4) ? row2hi : row2lo;
        float val = (l & 8) ? s2v : sv;
        wavered[wave][quad*4 + (l & 3) + 16*((l >> 2) & 1)][l >> 3] = val;
    }
    __syncthreads();
    if (tid < 32) {
        float s = 0.f, s2 = 0.f;
        #pragma unroll
        for (int w = 0; w < 4; ++w) { s += wavered[w][tid][0]; s2 += wavered[w][tid][1]; }
        float mu = s * (1.f/192.f);
        float var = s2 * (1.f/192.f) - mu*mu;
        smu[tid] = mu; srs[tid] = rsqrtf(var + 1e-5f);
    }
    __syncthreads();

    // ---- LN1 apply (elementwise in-place on x1, short8) ----
    #pragma unroll
    for (int it = 0; it < 3; ++it) {
        int idx = it*256 + tid;          // 768 = 32 tok * 24 groups
        int tok = idx / 24, g = idx - tok*24;
        float mu = smu[tok], rs = srs[tok];
        float4 ga = ((const float4*)(ln1g + g*8))[0], gb = ((const float4*)(ln1g + g*8))[1];
        float4 ba = ((const float4*)(ln1b + g*8))[0], bb = ((const float4*)(ln1b + g*8))[1];
        float gg[8]  = {ga.x,ga.y,ga.z,ga.w,gb.x,gb.y,gb.z,gb.w};
        float bbv[8] = {ba.x,ba.y,ba.z,ba.w,bb.x,bb.y,bb.z,bb.w};
        u16* p = arena + A_X1 + tok*S1 + g*8;
        short8 v = *(const short8*)p;
        short8 o;
        #pragma unroll
        for (int j = 0; j < 8; ++j)
            o[j] = (short)f2b((b2f((u16)v[j]) - mu)*rs*gg[j] + bbv[j]);
        *(short8*)p = o;
    }
    __syncthreads();

    // ---- FFN1 (relu) -> h (over dead ctx; x1 untouched at 12544+) ----
    {
        short8 Ax[2][6];
        load_afrags<6,2>(Ax, arena + A_X1, S1, lane16, quad);
        run_gemm<6,2,6>(Ax, ws + FW1_OFF, fb1, arena + A_H, nullptr, SH,
                        nullptr, 0, true, 1, 0, wave, lane16, quad);
    }
    __syncthreads();

    // ---- FFN2 (K=384) + LDS-resid(x1) -> x2 in regs; LN2 partials fused ----
    {
        float4v c2[3][2];
        #pragma unroll
        for (int i = 0; i < 3; ++i) { c2[i][0] = (float4v){0,0,0,0}; c2[i][1] = (float4v){0,0,0,0}; }
        #pragma unroll
        for (int kc = 0; kc < 2; ++kc) {
            short8 Af[2][6];
            load_afrags<6,2>(Af, arena + A_H + kc*192, SH, lane16, quad);
            #pragma unroll
            for (int i = 0; i < 3; ++i) {
                int nt = wave + 4*i;
                #pragma unroll
                for (int ks = 0; ks < 6; ++ks) {
                    short8 b = *(const short8*)(ws + FW2_OFF + ((nt*12 + kc*6 + ks)<<9) + (lane16<<5) + (quad<<3));
                    c2[i][0] = __builtin_amdgcn_mfma_f32_16x16x32_bf16(Af[0][ks], b, c2[i][0], 0,0,0);
                    c2[i][1] = __builtin_amdgcn_mfma_f32_16x16x32_bf16(Af[1][ks], b, c2[i][1], 0,0,0);
                }
            }
        }
        #pragma unroll
        for (int i = 0; i < 3; ++i) {
            int col = (wave + 4*i)*16 + lane16;
            float bv = fb2[col];
            #pragma unroll
            for (int mt = 0; mt < 2; ++mt)
                #pragma unroll
                for (int ii = 0; ii < 4; ++ii) {
                    int row = quad*4 + ii + 16*mt;
                    c2[i][mt][ii] += bv + b2f(arena[A_X1 + row*S1 + col]);
                }
        }
        // LN2 partials
        float sa[2][4], s2a[2][4];
        #pragma unroll
        for (int mt = 0; mt < 2; ++mt)
            #pragma unroll
            for (int ii = 0; ii < 4; ++ii) {
                float a0 = c2[0][mt][ii], a1 = c2[1][mt][ii], a2 = c2[2][mt][ii];
                float s = a0 + a1 + a2;
                float s2 = a0*a0 + a1*a1 + a2*a2;
                s  += __shfl_xor(s, 1);  s  += __shfl_xor(s, 2);
                s  += __shfl_xor(s, 4);  s  += __shfl_xor(s, 8);
                s2 += __shfl_xor(s2, 1); s2 += __shfl_xor(s2, 2);
                s2 += __shfl_xor(s2, 4); s2 += __shfl_xor(s2, 8);
                sa[mt][ii] = s; s2a[mt][ii] = s2;
            }
        int l = lane16;
        float rowlo = sel4(sa[0][0], sa[0][1], sa[0][2], sa[0][3], l & 3);
        float rowhi = sel4(sa[1][0], sa[1][1], sa[1][2], sa[1][3], l & 3);
        float row2lo = sel4(s2a[0][0], s2a[0][1], s2a[0][2], s2a[0][3], l & 3);
        float row2hi = sel4(s2a[1][0], s2a[1][1], s2a[1][2], s2a[1][3], l & 3);
        float sv = (l & 4) ? rowhi : rowlo;
        float s2v = (l & 4) ? row2hi : row2lo;
        float val = (l & 8) ? s2v : sv;
        wavered[wave][quad*4 + (l & 3) + 16*((l >> 2) & 1)][l >> 3] = val;
        __syncthreads();
        if (tid < 32) {
            float s = 0.f, s2 = 0.f;
            #pragma unroll
            for (int w = 0; w < 4; ++w) { s += wavered[w][tid][0]; s2 += wavered[w][tid][1]; }
            float mu = s * (1.f/192.f);
            float var = s2 * (1.f/192.f) - mu*mu;
            smu[tid] = mu; srs[tid] = rsqrtf(var + 1e-5f);
        }
        __syncthreads();
        // ---- LN2 apply + token-mean in-thread -> z (over dead h) ----
        #pragma unroll
        for (int i = 0; i < 3; ++i) {
            int col = (wave + 4*i)*16 + lane16;
            float g = ln2g[col], bb = ln2b[col];
            #pragma unroll
            for (int mt = 0; mt < 2; ++mt)
                #pragma unroll
                for (int p = 0; p < 2; ++p) {
                    int r = 2*quad + p + 8*mt;
                    float n0v = (c2[i][mt][2*p]   - smu[2*r  ]) * srs[2*r  ] * g + bb;
                    float n1v = (c2[i][mt][2*p+1] - smu[2*r+1]) * srs[2*r+1] * g + bb;
                    arena[A_Z + r*S1 + col] = f2b(0.5f*(n0v + n1v));
                }
        }
    }
    __syncthreads();

    // ---- heads: cls1 (relu -> ch), fingerprint (f32 -> fpf) ----
    {
        short8 A1[1][6];
        load_afrags<6,1>(A1, arena + A_Z, S1, lane16, quad);
        run_gemm<6,1,3>(A1, ws + CW1_OFF, cb1, arena + A_CH, nullptr, S1,
                        nullptr, 0, true, 1, 0, wave, lane16, quad);
        run_gemm<6,1,2>(A1, ws + FPW_OFF, fpb, nullptr, fpf, 128,
                        nullptr, 0, false, 1, 0, wave, lane16, quad);
    }
    __syncthreads();

    // ---- cls2+sigmoid (waves 0-2) || fp-norm partials (wave 3) ----
    if (tid < 192) {
        int g4 = tid >> 2, sub = tid & 3;
        int r = g4 / 3, cc = g4 - r*3;
        const float* w = cw2 + (size_t)cc * D + sub*48;
        const u16* hr = arena + A_CH + r*S1 + sub*48;
        float a = 0.f;
        #pragma unroll
        for (int i = 0; i < 6; ++i) {
            short8 hv = *(const short8*)(hr + i*8);
            float4 w0 = ((const float4*)w)[2*i], w1 = ((const float4*)w)[2*i+1];
            float wv[8] = {w0.x,w0.y,w0.z,w0.w,w1.x,w1.y,w1.z,w1.w};
            #pragma unroll
            for (int j = 0; j < 8; ++j) a += wv[j] * b2f((u16)hv[j]);
        }
        a += __shfl_xor(a, 1); a += __shfl_xor(a, 2);
        if (sub == 0) {
            a += cb2[cc];
            out[(size_t)cc * B + (size_t)(row0 + r)] = 1.f / (1.f + expf(-a));
        }
    } else {
        int t = tid - 192;               // 64 threads: 16 rows x 4-lane split
        int r = t >> 2, sub = t & 3;
        const float4* fp4 = (const float4*)(fpf + r*128 + sub*32);
        float s2 = 0.f;
        #pragma unroll
        for (int i = 0; i < 8; ++i) {
            float4 v = fp4[i];
            s2 += v.x*v.x + v.y*v.y + v.z*v.z + v.w*v.w;
        }
        s2 += __shfl_xor(s2, 1); s2 += __shfl_xor(s2, 2);
        if (sub == 0) srn[r] = 1.f / fmaxf(sqrtf(s2), 1e-12f);
    }
    __syncthreads();

    // ---- fingerprint writeout (float4) ----
    #pragma unroll
    for (int it = 0; it < 2; ++it) {
        int idx = it*256 + tid;          // 512 = 16 r * 32 float4
        int r = idx >> 5, c = idx & 31;
        float4 v = ((const float4*)(fpf + r*128))[c];
        float sc = srn[r];
        float4 o; o.x = v.x*sc; o.y = v.y*sc; o.z = v.z*sc; o.w = v.w*sc;
        ((float4*)(out + (size_t)3*B + (size_t)(row0 + r)*128))[c] = o;
    }
}

extern "C" void kernel_launch(void* const* d_in, const int* in_sizes, int n_in,
                              void* d_out, int out_size, void* d_ws, size_t ws_size,
                              hipStream_t stream) {
    if (ws_size < (size_t)W_TOTAL * 2) return;   // visible failure -> ws too small

    const float* perc = (const float*)d_in[0];
    const float* tech = (const float*)d_in[1];
    const float* Wp   = (const float*)d_in[2];
    const float* bp   = (const float*)d_in[3];
    const float* Wt   = (const float*)d_in[4];
    const float* bt   = (const float*)d_in[5];
    const float* in_w = (const float*)d_in[6];
    const float* in_b = (const float*)d_in[7];
    const float* ow   = (const float*)d_in[8];
    const float* ob   = (const float*)d_in[9];
    const float* fw1  = (const float*)d_in[10];
    const float* fb1  = (const float*)d_in[11];
    const float* fw2  = (const float*)d_in[12];
    const float* fb2  = (const float*)d_in[13];
    const float* ln1g = (const float*)d_in[14];
    const float* ln1b = (const float*)d_in[15];
    const float* ln2g = (const float*)d_in[16];
    const float* ln2b = (const float*)d_in[17];
    const float* cw1  = (const float*)d_in[18];
    const float* cb1  = (const float*)d_in[19];
    const float* cw2  = (const float*)d_in[20];
    const float* cb2  = (const float*)d_in[21];
    const float* fpw  = (const float*)d_in[22];
    const float* fpb  = (const float*)d_in[23];

    u16* ws = (u16*)d_ws;
    int B = in_sizes[0] / D;

    hipLaunchKernelGGL(cvt_weights, dim3((W_TOTAL + 255)/256), dim3(256), 0, stream,
                       Wp, Wt, in_w, ow, fw1, fw2, cw1, fpw, ws);

    hipLaunchKernelGGL(fusion_mfma_kernel, dim3(B / RPB), dim3(256), 0, stream,
                       perc, tech, bp, bt, in_b, ob, fb1, fb2,
                       ln1g, ln1b, ln2g, ln2b, cb1, cw2, cb2, fpb,
                       ws, (float*)d_out, B);
}